// Round 15
// baseline (264.868 us; speedup 1.0000x reference)
//
#include <hip/hip_runtime.h>
#include <math.h>

typedef unsigned long long u64;
typedef unsigned int u32;

#define NB 16
#define SL 1024
#define DIM 16
#define KNN 8
#define CH 64    /* coors hidden */
#define NHID 32  /* node hidden */
#define LN_EPS 1e-5f
#define PST 144  /* P row stride: 4 chunks of 36 (33 units + 3 zero pad) */
#define KSTR 148 /* knn lst scratch: words per slice (16 q * 9 + 4 pad; odd-ish stride vs banks) */

// silu via hw exp + hw rcp: 5 VALU vs ~12 for div-based (no -ffast-math here)
__device__ __forceinline__ float silu_f(float x) {
    const float e = __expf(-x);
    return x * __builtin_amdgcn_rcpf(1.0f + e);
}

// ---------------- init: feats/coords copy + fused phi for layer 0 ----------------
__global__ __launch_bounds__(256) void init_kernel(
    const float* __restrict__ coords, const int* __restrict__ residues,
    const float* __restrict__ token_emb, const float* __restrict__ pos_emb,
    const float* __restrict__ w1tp, const float* __restrict__ g_eb1,
    float* __restrict__ coordsA, float* __restrict__ featsA,
    float* __restrict__ Pout)
{
    const int t = blockIdx.x * 256 + threadIdx.x;
    const int node = t >> 2;
    const int part = t & 3;
    const int l = node & (SL - 1);
    const int r = residues[node];
    float f[16];
    {
        const float4* te = (const float4*)(token_emb + (size_t)r * DIM);
        const float4* pe = (const float4*)(pos_emb + (size_t)l * DIM);
#pragma unroll
        for (int q = 0; q < 4; ++q) {
            float4 a = te[q], b4 = pe[q];
            f[4*q+0] = a.x + b4.x; f[4*q+1] = a.y + b4.y;
            f[4*q+2] = a.z + b4.z; f[4*q+3] = a.w + b4.w;
        }
    }
    if (part == 0) {
        float4* fo = (float4*)(featsA + (size_t)node * DIM);
#pragma unroll
        for (int q = 0; q < 4; ++q)
            fo[q] = make_float4(f[4*q], f[4*q+1], f[4*q+2], f[4*q+3]);
        coordsA[node * 3 + 0] = coords[node * 3 + 0];
        coordsA[node * 3 + 1] = coords[node * 3 + 1];
        coordsA[node * 3 + 2] = coords[node * 3 + 2];
    }
    const int ubase = (part & 1) * 33;
    const int wbase = (part < 2) ? 0 : 66;
    float res[36];
    res[33] = 0.f; res[34] = 0.f; res[35] = 0.f;
#pragma unroll
    for (int oo = 0; oo < 33; ++oo) {     // FULL unroll: res[] stays in registers
        const int u = ubase + oo;
        const float* wr = w1tp + (wbase + u) * 16;
        float a0 = (part < 2) ? g_eb1[u] : 0.0f;
        float a1 = 0.f, a2 = 0.f, a3 = 0.f;
#pragma unroll
        for (int c = 0; c < 16; c += 4) {
            a0 = fmaf(f[c + 0], wr[c + 0], a0);
            a1 = fmaf(f[c + 1], wr[c + 1], a1);
            a2 = fmaf(f[c + 2], wr[c + 2], a2);
            a3 = fmaf(f[c + 3], wr[c + 3], a3);
        }
        res[oo] = (a0 + a1) + (a2 + a3);
    }
    float4* op = (float4*)(Pout + (size_t)node * PST + part * 36);
#pragma unroll
    for (int q = 0; q < 9; ++q)
        op[q] = make_float4(res[4*q], res[4*q+1], res[4*q+2], res[4*q+3]);
}

// ---------------- weight transpose/pack ----------------
__global__ __launch_bounds__(256) void pack_kernel(
    const float* __restrict__ ew1, const float* __restrict__ ew2,
    const float* __restrict__ cw1,
    const float* __restrict__ nw1, const float* __restrict__ nw2,
    float* __restrict__ w1tp, float* __restrict__ w1rp, float* __restrict__ w2p,
    float* __restrict__ cw1t, float* __restrict__ nw1t, float* __restrict__ nw2t)
{
    const int stride = gridDim.x * 256;
    const int t0 = blockIdx.x * 256 + threadIdx.x;
    for (int idx = t0; idx < 3 * 132 * 16; idx += stride) {
        int d = idx / (132 * 16); int r = idx - d * 132 * 16; int o = r >> 4; int c = r & 15;
        int u = (o < 66) ? o : (o - 66);
        int cc = (o < 66) ? c : (16 + c);
        w1tp[idx] = ew1[(d * 33 + cc) * 66 + u];
    }
    for (int idx = t0; idx < 3 * 72; idx += stride) {
        int d = idx / 72; int o = idx - d * 72; int hh = o / 36; int uu = o - hh * 36;
        w1rp[idx] = (uu < 33) ? ew1[(d * 33 + 32) * 66 + hh * 33 + uu] : 0.0f;
    }
    for (int idx = t0; idx < 3 * 72 * 16; idx += stride) {
        int d = idx / (72 * 16); int r = idx - d * 72 * 16; int u = r >> 4; int v = r & 15;
        int hh = u / 36; int uu = u - hh * 36;
        w2p[idx] = (uu < 33) ? ew2[(d * 66 + hh * 33 + uu) * 16 + v] : 0.0f;
    }
    for (int idx = t0; idx < 3 * CH * 16; idx += stride) {
        int d = idx / (CH * 16); int r = idx - d * CH * 16; int t = r >> 4; int v = r & 15;
        cw1t[(d * CH + t) * 16 + v] = cw1[(d * 16 + v) * CH + t];
    }
    for (int idx = t0; idx < 3 * NHID * 32; idx += stride) {
        int d = idx / (NHID * 32); int r = idx - d * NHID * 32; int u = r >> 5; int c = r & 31;
        nw1t[(d * NHID + u) * 32 + c] = nw1[(d * 32 + c) * NHID + u];
    }
    for (int idx = t0; idx < 3 * 16 * 32; idx += stride) {
        int d = idx / (16 * 32); int r = idx - d * 16 * 32; int c = r >> 5; int u = r & 31;
        nw2t[(d * 16 + c) * 32 + u] = nw2[(d * 32 + u) * 16 + c];
    }
}

__device__ __forceinline__ void merge8(u32* a, const u32* bb) {
    u32 c[8];
#pragma unroll
    for (int t = 0; t < 8; ++t) c[t] = min(a[t], bb[7 - t]);
#define MCAS(x, y) { u32 mn = min(c[x], c[y]); u32 mx = max(c[x], c[y]); c[x] = mn; c[y] = mx; }
    MCAS(0, 4) MCAS(1, 5) MCAS(2, 6) MCAS(3, 7)
    MCAS(0, 2) MCAS(1, 3) MCAS(4, 6) MCAS(5, 7)
    MCAS(0, 1) MCAS(2, 3) MCAS(4, 5) MCAS(6, 7)
#undef MCAS
#pragma unroll
    for (int t = 0; t < 8; ++t) a[t] = c[t];
}

// ---------------- FUSED knn+layer for one d, 16 nodes/block, 4 blocks/CU ----------------
// r14 post-mortem: (256,4) squeezed VGPR to 64 -> spills (WRITE 21MB); s=tid>>4 made
// the candidate loop's 4 concurrent slice reads alias to the same banks (6.99M confl).
// Fixes: (256,3) for VGPR headroom (r13 precedent: 92, clean); rotated candidate visit
// j=jbase+((jj+s)&63) -> disjoint bank quads (bitwise-safe: top-8 is order-independent);
// merge scratch s-stride 148 (16*9 stride had level-1 reads 0 mod 32).
// Cooperative launch NOT capture-safe (r12). 1e5 sentinel load-bearing (r4/r5).
__global__ __launch_bounds__(256, 3) void fused_kernel(
    const int d,
    const float* __restrict__ coordsIn, float* __restrict__ coordsOut,
    const float* __restrict__ featsIn, float* __restrict__ featsOut,
    const float* __restrict__ Pbuf, float* __restrict__ PbufOut,
    int* __restrict__ idxbuf, const int* __restrict__ lengths,
    const float* __restrict__ w1rp, const float* __restrict__ w2p,
    const float* __restrict__ g_eb2,
    const float* __restrict__ cw1t, const float* __restrict__ g_cb1,
    const float* __restrict__ g_cw2, const float* __restrict__ g_cb2,
    const float* __restrict__ g_lng, const float* __restrict__ g_lnb,
    const float* __restrict__ nw1t, const float* __restrict__ g_nb1,
    const float* __restrict__ nw2t, const float* __restrict__ g_nb2,
    const float* __restrict__ w1tp_all, const float* __restrict__ g_eb1,
    const float* __restrict__ fw, const float* __restrict__ fb,
    float* __restrict__ gout)
{
    __shared__ __align__(16) char smem[16384 + KSTR * 16 * 4];   // 25856 B
    const int tid = threadIdx.x;
    const int lane = tid & 63;

    // ================= kNN phase: 16 queries, 16 slices x 64 candidates =================
    {
        float4* s_cand = (float4*)smem;                 // 16384 B
        u32* lst_base  = (u32*)(smem + 16384);          // 16*KSTR*4 = 9472 B
        const int bk = blockIdx.x >> 6;                 // 64 blocks per batch
        const int i0 = (blockIdx.x & 63) << 4;          // 16 queries/block
        const int len = lengths[bk];
        const float* cb = coordsIn + (size_t)bk * SL * 3;
        for (int idx = tid; idx < SL; idx += 256) {
            const float* cp = cb + idx * 3;
            s_cand[idx] = make_float4(cp[0], cp[1], cp[2], 0.0f);
        }
        __syncthreads();

        const int q = tid & 15;
        const int s = tid >> 4;                          // slice 0..15
        const int i = i0 + q;
        const bool mi = i < len;
        const float4 qi = s_cand[i];
        const float xi = qi.x, yi = qi.y, zi = qi.z;

        u32 lst[8];
#pragma unroll
        for (int t = 0; t < 8; ++t) lst[t] = 0xFFFFFFFFu;

        const int jbase = s << 6;
#pragma unroll 4
        for (int jj = 0; jj < 64; ++jj) {
            const int j = jbase + ((jj + s) & 63);       // rotated visit: bank-disjoint
            const float4 cj = s_cand[j];
            const float dx = xi - cj.x, dy = yi - cj.y, dz = zi - cj.z;
            const float dist = dx * dx + dy * dy + dz * dz;
            const int dij = j - i;
            const bool pm = mi && (j < len);
            const bool adjx = (dij == 1) | (dij == -1);
            float v = pm ? (adjx ? 0.0f : dist) : 1e5f;
            v = (dij == 0) ? -1.0f : v;
            u32 bits = __float_as_uint(v);
            bits ^= (u32)((int)bits >> 31) | 0x80000000u;
            const u32 key = (bits & 0xFFFFFC00u) | (u32)j;
#pragma unroll
            for (int p = 7; p >= 1; --p)
                lst[p] = min(max(key, lst[p - 1]), lst[p]);
            lst[0] = min(key, lst[0]);
        }
#pragma unroll
        for (int t = 0; t < 8; ++t) lst_base[s * KSTR + q * 9 + t] = lst[t];
        __syncthreads();

        if (tid < 128) {
            const int p = tid >> 4, qq = tid & 15;
            u32 a[8], bb[8];
#pragma unroll
            for (int t = 0; t < 8; ++t) {
                a[t]  = lst_base[(2 * p) * KSTR + qq * 9 + t];
                bb[t] = lst_base[(2 * p + 1) * KSTR + qq * 9 + t];
            }
            merge8(a, bb);
#pragma unroll
            for (int t = 0; t < 8; ++t) lst_base[(2 * p) * KSTR + qq * 9 + t] = a[t];
        }
        __syncthreads();
        if (tid < 64) {
            const int p = tid >> 4, qq = tid & 15;
            u32 a[8], bb[8];
#pragma unroll
            for (int t = 0; t < 8; ++t) {
                a[t]  = lst_base[(4 * p) * KSTR + qq * 9 + t];
                bb[t] = lst_base[(4 * p + 2) * KSTR + qq * 9 + t];
            }
            merge8(a, bb);
#pragma unroll
            for (int t = 0; t < 8; ++t) lst_base[(4 * p) * KSTR + qq * 9 + t] = a[t];
        }
        __syncthreads();
        if (tid < 32) {
            const int p = tid >> 4, qq = tid & 15;
            u32 a[8], bb[8];
#pragma unroll
            for (int t = 0; t < 8; ++t) {
                a[t]  = lst_base[(8 * p) * KSTR + qq * 9 + t];
                bb[t] = lst_base[(8 * p + 4) * KSTR + qq * 9 + t];
            }
            merge8(a, bb);
#pragma unroll
            for (int t = 0; t < 8; ++t) lst_base[(8 * p) * KSTR + qq * 9 + t] = a[t];
        }
        __syncthreads();
        if (tid < 16) {
            const int qq = tid;
            u32 a[8], bb[8];
#pragma unroll
            for (int t = 0; t < 8; ++t) {
                a[t]  = lst_base[0 * KSTR + qq * 9 + t];
                bb[t] = lst_base[8 * KSTR + qq * 9 + t];
            }
            merge8(a, bb);
            const size_t node = (size_t)bk * SL + i0 + qq;
            int4 r0 = make_int4((int)(a[0] & 1023u), (int)(a[1] & 1023u), (int)(a[2] & 1023u), (int)(a[3] & 1023u));
            int4 r1 = make_int4((int)(a[4] & 1023u), (int)(a[5] & 1023u), (int)(a[6] & 1023u), (int)(a[7] & 1023u));
            ((int4*)idxbuf)[node * 2 + 0] = r0;
            ((int4*)idxbuf)[node * 2 + 1] = r1;
        }
    }
    __syncthreads();   // knn LDS readers done; this block's idxbuf rows visible (same L1)

    // ================= layer phase (r8 1-node lane-swap body) =================
    {
        float* s_w2e  = (float*)(smem);
        float* s_cw1  = (float*)(smem + 4608);
        float* s_nw1  = (float*)(smem + 8704);
        float* s_nw2  = (float*)(smem + 13312);
        float* s_w1r  = (float*)(smem + 15616);
        float* s_cw2v = (float*)(smem + 15904);
        float* s_cb1  = (float*)(smem + 16160);
        float* s_eb2  = (float*)(smem + 16416);
        float* s_lng  = (float*)(smem + 16480);
        float* s_lnb  = (float*)(smem + 16544);
        float* s_nb1  = (float*)(smem + 16608);
        float* s_nb2  = (float*)(smem + 16736);
        float* s_cb2  = (float*)(smem + 16800);

        for (int t = tid; t < 72 * 16; t += 256) s_w2e[t] = w2p[d * 72 * 16 + t];
        for (int t = tid; t < CH * 16; t += 256) s_cw1[t] = cw1t[d * CH * 16 + t];
        for (int t = tid; t < NHID * 32; t += 256) s_nw1[(t >> 5) * 36 + (t & 31)] = nw1t[d * NHID * 32 + t];
        for (int t = tid; t < 16 * 32; t += 256) s_nw2[(t >> 5) * 36 + (t & 31)] = nw2t[d * 16 * 32 + t];
        if (tid < 72) s_w1r[tid] = w1rp[d * 72 + tid];
        if (tid < CH) { s_cw2v[tid] = g_cw2[d * CH + tid]; s_cb1[tid] = g_cb1[d * CH + tid]; }
        if (tid < 16) {
            s_eb2[tid] = g_eb2[d * 16 + tid];
            s_lng[tid] = g_lng[d * 16 + tid];
            s_lnb[tid] = g_lnb[d * 16 + tid];
            s_nb2[tid] = g_nb2[d * 16 + tid];
        }
        if (tid < 32) s_nb1[tid] = g_nb1[d * 32 + tid];
        if (tid == 0) s_cb2[0] = g_cb2[d];

        const int h = (lane >> 3) & 1;
        const int k = lane & 7;
        const int sub = lane & 15;
        const int n = blockIdx.x * 16 + (tid >> 4);
        const int b = n >> 10;
        const int len = lengths[b];
        const int j = idxbuf[n * 8 + k];
        const bool em = ((n & 1023) < len) && (j < len);

        float ci[3], rel[3];
        {
            const float* cp = coordsIn + (size_t)n * 3;
            const float* cq = coordsIn + ((size_t)b * SL + j) * 3;
            ci[0] = cp[0]; ci[1] = cp[1]; ci[2] = cp[2];
            rel[0] = ci[0] - cq[0]; rel[1] = ci[1] - cq[1]; rel[2] = ci[2] - cq[2];
        }
        const float rd = fmaf(rel[0], rel[0], fmaf(rel[1], rel[1], rel[2] * rel[2]));

        const int ub = h * 36;
        const float* PiP = Pbuf + (size_t)n * PST + ub;
        const float* PjP = Pbuf + ((size_t)b * SL + j) * PST + 72 + ub;
        float4 pa = *(const float4*)PiP;
        float4 pb = *(const float4*)PjP;

        __syncthreads();   // weights staged

        float macc[16];
#pragma unroll
        for (int v = 0; v < 16; ++v) macc[v] = h ? 0.0f : s_eb2[v];
#pragma unroll
        for (int c4 = 0; c4 < 9; ++c4) {
            float4 na, nb;
            if (c4 < 8) {
                na = *(const float4*)(PiP + 4 * (c4 + 1));
                nb = *(const float4*)(PjP + 4 * (c4 + 1));
            }
            const int u0 = ub + c4 * 4;
            const float4 w1r4 = *(const float4*)&s_w1r[u0];
            const float hu0 = silu_f(fmaf(rd, w1r4.x, pa.x + pb.x));
            const float hu1 = silu_f(fmaf(rd, w1r4.y, pa.y + pb.y));
            const float hu2 = silu_f(fmaf(rd, w1r4.z, pa.z + pb.z));
            const float hu3 = silu_f(fmaf(rd, w1r4.w, pa.w + pb.w));
            const float* w2r = &s_w2e[u0 * 16];
#pragma unroll
            for (int v = 0; v < 16; ++v) {
                float m0 = fmaf(hu0, w2r[v], macc[v]);
                float m1 = fmaf(hu1, w2r[16 + v], m0);
                float m2 = fmaf(hu2, w2r[32 + v], m1);
                macc[v] = fmaf(hu3, w2r[48 + v], m2);
            }
            if (c4 < 8) { pa = na; pb = nb; }
        }

        // combine halves in-wave (partner = lane^8): macc becomes mm in place
#pragma unroll
        for (int v = 0; v < 16; ++v)
            macc[v] = silu_f(macc[v] + __shfl_xor(macc[v], 8, 64));

        const int tb = h * 32;
        float wa = 0.f;
#pragma unroll 4
        for (int tt = 0; tt < 32; ++tt) {
            const float* cr = &s_cw1[(tb + tt) * 16];
            float a0 = s_cb1[tb + tt], a1 = 0.f;
#pragma unroll
            for (int v = 0; v < 16; v += 2) {
                a0 = fmaf(macc[v], cr[v], a0);
                a1 = fmaf(macc[v + 1], cr[v + 1], a1);
            }
            wa = fmaf(silu_f(a0 + a1), s_cw2v[tb + tt], wa);
        }
        const float wao = __shfl_xor(wa, 8, 64);
        const float we = em ? (wa + wao + s_cb2[0]) : 0.f;

        float wr0 = we * rel[0], wr1 = we * rel[1], wr2 = we * rel[2];
#pragma unroll
        for (int s = 1; s < 8; s <<= 1) {
            wr0 += __shfl_xor(wr0, s, 64);
            wr1 += __shfl_xor(wr1, s, 64);
            wr2 += __shfl_xor(wr2, s, 64);
        }
        if ((lane & 15) == 0) {
            coordsOut[(size_t)n * 3 + 0] = ci[0] + wr0;
            coordsOut[(size_t)n * 3 + 1] = ci[1] + wr1;
            coordsOut[(size_t)n * 3 + 2] = ci[2] + wr2;
        }

        // m_i in place
#pragma unroll
        for (int v = 0; v < 16; ++v) {
            macc[v] = em ? macc[v] : 0.f;
#pragma unroll
            for (int s = 1; s < 8; s <<= 1)
                macc[v] += __shfl_xor(macc[v], s, 64);
        }
        // macc now holds m_i.

        float fi[16];
        {
            const float4* pp = (const float4*)(featsIn + (size_t)n * DIM);
            float4 a0 = pp[0], a1 = pp[1], a2 = pp[2], a3 = pp[3];
            fi[0]=a0.x; fi[1]=a0.y; fi[2]=a0.z; fi[3]=a0.w;
            fi[4]=a1.x; fi[5]=a1.y; fi[6]=a1.z; fi[7]=a1.w;
            fi[8]=a2.x; fi[9]=a2.y; fi[10]=a2.z; fi[11]=a2.w;
            fi[12]=a3.x; fi[13]=a3.y; fi[14]=a3.z; fi[15]=a3.w;
        }
        const float fiSub = featsIn[(size_t)n * DIM + sub];   // residual channel

        // LayerNorm: fi becomes nn in place
        {
            float mu = 0.f;
#pragma unroll
            for (int c = 0; c < 16; ++c) mu += fi[c];
            mu *= 0.0625f;
            float var = 0.f;
#pragma unroll
            for (int c = 0; c < 16; ++c) { const float dd = fi[c] - mu; var = fmaf(dd, dd, var); }
            var *= 0.0625f;
            const float rs = rsqrtf(var + LN_EPS);
#pragma unroll
            for (int c = 0; c < 16; ++c) fi[c] = fmaf((fi[c] - mu) * rs, s_lng[c], s_lnb[c]);
        }

        float nh[2];
#pragma unroll
        for (int q2 = 0; q2 < 2; ++q2) {
            const int u = sub * 2 + q2;
            const float* nr = &s_nw1[u * 36];
            float a0 = s_nb1[u], a1 = 0.f;
#pragma unroll
            for (int c = 0; c < 16; c += 2) {
                a0 = fmaf(fi[c], nr[c], a0);
                a1 = fmaf(fi[c + 1], nr[c + 1], a1);
            }
#pragma unroll
            for (int v = 0; v < 16; v += 2) {
                a0 = fmaf(macc[v], nr[16 + v], a0);
                a1 = fmaf(macc[v + 1], nr[16 + v + 1], a1);
            }
            nh[q2] = silu_f(a0 + a1);
        }

        const int nbase = lane & ~15;
        const float* w2c = &s_nw2[sub * 36];
        float o0 = s_nb2[sub];
#pragma unroll
        for (int u = 0; u < 32; ++u) {
            const float v = __shfl(nh[u & 1], nbase + (u >> 1), 64);
            o0 = fmaf(v, w2c[u], o0);
        }
        const float fo = fiSub + o0;
        featsOut[(size_t)n * DIM + sub] = fo;

        // gather new feats row (phi for d<2; final for d==2)
        float fr[16];
#pragma unroll
        for (int c = 0; c < 16; ++c) fr[c] = __shfl(fo, nbase + c, 64);

        if (d < 2) {
            const float* wbase = w1tp_all + (d + 1) * 132 * 16;
            const float* bbase = g_eb1 + (d + 1) * 66;
            float* Pout = PbufOut + (size_t)n * PST;
#pragma unroll
            for (int q2 = 0; q2 < 9; ++q2) {
                const int col = sub + (q2 << 4);
                const int ch = (col >= 108) ? 3 : (col >= 72) ? 2 : (col >= 36) ? 1 : 0;
                const int uu = col - ch * 36;
                const bool valid = uu < 33;
                const int u = ((ch & 1) ? 33 : 0) + uu;
                const int uc = valid ? u : 0;
                const int widx = valid ? ((ch < 2) ? u : 66 + u) : 0;
                float a0 = (valid && ch < 2) ? bbase[uc] : 0.0f;
                float a1 = 0.f, a2 = 0.f, a3 = 0.f;
                const float* wr = wbase + widx * 16;
#pragma unroll
                for (int cc = 0; cc < 16; cc += 4) {
                    a0 = fmaf(fr[cc + 0], wr[cc + 0], a0);
                    a1 = fmaf(fr[cc + 1], wr[cc + 1], a1);
                    a2 = fmaf(fr[cc + 2], wr[cc + 2], a2);
                    a3 = fmaf(fr[cc + 3], wr[cc + 3], a3);
                }
                Pout[col] = valid ? ((a0 + a1) + (a2 + a3)) : 0.0f;
            }
        } else {
            // fused final projection: lanes sub<3 compute output channel sub
            if (sub < 3) {
                float acc = fb[sub];
#pragma unroll
                for (int c = 0; c < 16; ++c)
                    acc = fmaf(fr[c], fw[c * 3 + sub], acc);
                gout[(size_t)n * 3 + sub] = acc;
            }
        }
    }
}

extern "C" void kernel_launch(void* const* d_in, const int* in_sizes, int n_in,
                              void* d_out, int out_size, void* d_ws, size_t ws_size,
                              hipStream_t stream) {
    const float* coords    = (const float*)d_in[0];
    const int*   residues  = (const int*)d_in[1];
    const int*   lengths   = (const int*)d_in[2];
    const float* token_emb = (const float*)d_in[3];
    const float* pos_emb   = (const float*)d_in[4];
    const float* ew1 = (const float*)d_in[5];
    const float* eb1 = (const float*)d_in[6];
    const float* ew2 = (const float*)d_in[7];
    const float* eb2 = (const float*)d_in[8];
    const float* cw1 = (const float*)d_in[9];
    const float* cb1 = (const float*)d_in[10];
    const float* cw2 = (const float*)d_in[11];
    const float* cb2 = (const float*)d_in[12];
    const float* lng = (const float*)d_in[13];
    const float* lnb = (const float*)d_in[14];
    const float* nw1 = (const float*)d_in[15];
    const float* nb1 = (const float*)d_in[16];
    const float* nw2 = (const float*)d_in[17];
    const float* nb2 = (const float*)d_in[18];
    const float* fw  = (const float*)d_in[19];
    const float* fb  = (const float*)d_in[20];

    float* ws = (float*)d_ws;
    float* coordsA = ws;
    float* coordsB = coordsA + NB * SL * 3;
    float* featsA  = coordsB + NB * SL * 3;
    float* featsB  = featsA + NB * SL * DIM;
    int*   idxbuf  = (int*)(featsB + NB * SL * DIM);
    float* w1tp = (float*)(idxbuf + NB * SL * KNN);     // 3*132*16
    float* w1rp = w1tp + 3 * 132 * 16;                  // 3*72
    float* w2p  = w1rp + 3 * 72;                        // 3*72*16
    float* cw1t = w2p + 3 * 72 * 16;                    // 3*64*16
    float* nw1t = cw1t + 3 * CH * 16;                   // 3*32*32
    float* nw2t = nw1t + 3 * NHID * 32;                 // 3*16*32
    float* PbufA = nw2t + 3 * 16 * 32;                  // 16384*144
    float* PbufB = PbufA + (size_t)NB * SL * PST;       // 16384*144
    float* gout  = (float*)d_out;

    pack_kernel<<<32, 256, 0, stream>>>(ew1, ew2, cw1, nw1, nw2, w1tp, w1rp, w2p, cw1t, nw1t, nw2t);
    init_kernel<<<NB * SL * 4 / 256, 256, 0, stream>>>(coords, residues, token_emb, pos_emb,
                                                        w1tp, eb1, coordsA, featsA, PbufA);

    float* cIn = coordsA; float* cOut = coordsB;
    float* fIn = featsA;  float* fOut = featsB;
    float* pIn = PbufA;   float* pOut = PbufB;
    for (int d = 0; d < 3; ++d) {
        fused_kernel<<<NB * SL / 16, 256, 0, stream>>>(d, cIn, cOut, fIn, fOut, pIn, pOut,
            idxbuf, lengths,
            w1rp, w2p, eb2, cw1t, cb1, cw2, cb2, lng, lnb, nw1t, nb1, nw2t, nb2,
            w1tp, eb1, fw, fb, gout);
        float* t;
        t = cIn; cIn = cOut; cOut = t;
        t = fIn; fIn = fOut; fOut = t;
        t = pIn; pIn = pOut; pOut = t;
    }
}

// Round 16
// 263.745 us; speedup vs baseline: 1.0043x; 1.0043x over previous
//
#include <hip/hip_runtime.h>
#include <math.h>

typedef unsigned long long u64;
typedef unsigned int u32;

#define NB 16
#define SL 1024
#define DIM 16
#define KNN 8
#define CH 64    /* coors hidden */
#define NHID 32  /* node hidden */
#define LN_EPS 1e-5f
#define PST 144  /* P row stride: 4 chunks of 36 (33 units + 3 zero pad) */
#define KSTR 148 /* knn lst scratch: words per slice (16 q * 9 + 4 pad; odd-ish stride vs banks) */

// silu via hw exp + hw rcp: 5 VALU vs ~12 for div-based (no -ffast-math here)
__device__ __forceinline__ float silu_f(float x) {
    const float e = __expf(-x);
    return x * __builtin_amdgcn_rcpf(1.0f + e);
}

// ---------------- init: feats/coords copy + fused phi for layer 0 ----------------
__global__ __launch_bounds__(256) void init_kernel(
    const float* __restrict__ coords, const int* __restrict__ residues,
    const float* __restrict__ token_emb, const float* __restrict__ pos_emb,
    const float* __restrict__ w1tp, const float* __restrict__ g_eb1,
    float* __restrict__ coordsA, float* __restrict__ featsA,
    float* __restrict__ Pout)
{
    const int t = blockIdx.x * 256 + threadIdx.x;
    const int node = t >> 2;
    const int part = t & 3;
    const int l = node & (SL - 1);
    const int r = residues[node];
    float f[16];
    {
        const float4* te = (const float4*)(token_emb + (size_t)r * DIM);
        const float4* pe = (const float4*)(pos_emb + (size_t)l * DIM);
#pragma unroll
        for (int q = 0; q < 4; ++q) {
            float4 a = te[q], b4 = pe[q];
            f[4*q+0] = a.x + b4.x; f[4*q+1] = a.y + b4.y;
            f[4*q+2] = a.z + b4.z; f[4*q+3] = a.w + b4.w;
        }
    }
    if (part == 0) {
        float4* fo = (float4*)(featsA + (size_t)node * DIM);
#pragma unroll
        for (int q = 0; q < 4; ++q)
            fo[q] = make_float4(f[4*q], f[4*q+1], f[4*q+2], f[4*q+3]);
        coordsA[node * 3 + 0] = coords[node * 3 + 0];
        coordsA[node * 3 + 1] = coords[node * 3 + 1];
        coordsA[node * 3 + 2] = coords[node * 3 + 2];
    }
    const int ubase = (part & 1) * 33;
    const int wbase = (part < 2) ? 0 : 66;
    float res[36];
    res[33] = 0.f; res[34] = 0.f; res[35] = 0.f;
#pragma unroll
    for (int oo = 0; oo < 33; ++oo) {     // FULL unroll: res[] stays in registers
        const int u = ubase + oo;
        const float* wr = w1tp + (wbase + u) * 16;
        float a0 = (part < 2) ? g_eb1[u] : 0.0f;
        float a1 = 0.f, a2 = 0.f, a3 = 0.f;
#pragma unroll
        for (int c = 0; c < 16; c += 4) {
            a0 = fmaf(f[c + 0], wr[c + 0], a0);
            a1 = fmaf(f[c + 1], wr[c + 1], a1);
            a2 = fmaf(f[c + 2], wr[c + 2], a2);
            a3 = fmaf(f[c + 3], wr[c + 3], a3);
        }
        res[oo] = (a0 + a1) + (a2 + a3);
    }
    float4* op = (float4*)(Pout + (size_t)node * PST + part * 36);
#pragma unroll
    for (int q = 0; q < 9; ++q)
        op[q] = make_float4(res[4*q], res[4*q+1], res[4*q+2], res[4*q+3]);
}

// ---------------- weight transpose/pack ----------------
__global__ __launch_bounds__(256) void pack_kernel(
    const float* __restrict__ ew1, const float* __restrict__ ew2,
    const float* __restrict__ cw1,
    const float* __restrict__ nw1, const float* __restrict__ nw2,
    float* __restrict__ w1tp, float* __restrict__ w1rp, float* __restrict__ w2p,
    float* __restrict__ cw1t, float* __restrict__ nw1t, float* __restrict__ nw2t)
{
    const int stride = gridDim.x * 256;
    const int t0 = blockIdx.x * 256 + threadIdx.x;
    for (int idx = t0; idx < 3 * 132 * 16; idx += stride) {
        int d = idx / (132 * 16); int r = idx - d * 132 * 16; int o = r >> 4; int c = r & 15;
        int u = (o < 66) ? o : (o - 66);
        int cc = (o < 66) ? c : (16 + c);
        w1tp[idx] = ew1[(d * 33 + cc) * 66 + u];
    }
    for (int idx = t0; idx < 3 * 72; idx += stride) {
        int d = idx / 72; int o = idx - d * 72; int hh = o / 36; int uu = o - hh * 36;
        w1rp[idx] = (uu < 33) ? ew1[(d * 33 + 32) * 66 + hh * 33 + uu] : 0.0f;
    }
    for (int idx = t0; idx < 3 * 72 * 16; idx += stride) {
        int d = idx / (72 * 16); int r = idx - d * 72 * 16; int u = r >> 4; int v = r & 15;
        int hh = u / 36; int uu = u - hh * 36;
        w2p[idx] = (uu < 33) ? ew2[(d * 66 + hh * 33 + uu) * 16 + v] : 0.0f;
    }
    for (int idx = t0; idx < 3 * CH * 16; idx += stride) {
        int d = idx / (CH * 16); int r = idx - d * CH * 16; int t = r >> 4; int v = r & 15;
        cw1t[(d * CH + t) * 16 + v] = cw1[(d * 16 + v) * CH + t];
    }
    for (int idx = t0; idx < 3 * NHID * 32; idx += stride) {
        int d = idx / (NHID * 32); int r = idx - d * NHID * 32; int u = r >> 5; int c = r & 31;
        nw1t[(d * NHID + u) * 32 + c] = nw1[(d * 32 + c) * NHID + u];
    }
    for (int idx = t0; idx < 3 * 16 * 32; idx += stride) {
        int d = idx / (16 * 32); int r = idx - d * 16 * 32; int c = r >> 5; int u = r & 31;
        nw2t[(d * 16 + c) * 32 + u] = nw2[(d * 32 + u) * 16 + c];
    }
}

__device__ __forceinline__ void merge8(u32* a, const u32* bb) {
    u32 c[8];
#pragma unroll
    for (int t = 0; t < 8; ++t) c[t] = min(a[t], bb[7 - t]);
#define MCAS(x, y) { u32 mn = min(c[x], c[y]); u32 mx = max(c[x], c[y]); c[x] = mn; c[y] = mx; }
    MCAS(0, 4) MCAS(1, 5) MCAS(2, 6) MCAS(3, 7)
    MCAS(0, 2) MCAS(1, 3) MCAS(4, 6) MCAS(5, 7)
    MCAS(0, 1) MCAS(2, 3) MCAS(4, 5) MCAS(6, 7)
#undef MCAS
#pragma unroll
    for (int t = 0; t < 8; ++t) a[t] = c[t];
}

// ---------------- FUSED knn+layer for one d, 16 nodes/block ----------------
// r15 post-mortem: launch_bounds 2nd arg empirically tracks RESIDENCY in this
// toolchain (arg=2/3/4 -> meas occ 20/24/30%); arg=3 cost a resident block and
// regressed despite clean VGPR + fewer conflicts. Fix: NO min-waves hint -- the
// allocator keeps natural ~72 VGPR (r15: spill-free) and residency is resource-
// limited only (VGPR 72 => 7 waves/SIMD; LDS 26.1KB => 6 blocks; grid => 4).
// Keep r15's rotated candidate visit (bank-disjoint, -2.1M conflicts, bitwise-safe)
// and KSTR=148 merge stride. Cooperative launch NOT capture-safe (r12).
// 1e5 sentinel load-bearing: do NOT length-clamp (r4/r5).
__global__ __launch_bounds__(256) void fused_kernel(
    const int d,
    const float* __restrict__ coordsIn, float* __restrict__ coordsOut,
    const float* __restrict__ featsIn, float* __restrict__ featsOut,
    const float* __restrict__ Pbuf, float* __restrict__ PbufOut,
    int* __restrict__ idxbuf, const int* __restrict__ lengths,
    const float* __restrict__ w1rp, const float* __restrict__ w2p,
    const float* __restrict__ g_eb2,
    const float* __restrict__ cw1t, const float* __restrict__ g_cb1,
    const float* __restrict__ g_cw2, const float* __restrict__ g_cb2,
    const float* __restrict__ g_lng, const float* __restrict__ g_lnb,
    const float* __restrict__ nw1t, const float* __restrict__ g_nb1,
    const float* __restrict__ nw2t, const float* __restrict__ g_nb2,
    const float* __restrict__ w1tp_all, const float* __restrict__ g_eb1,
    const float* __restrict__ fw, const float* __restrict__ fb,
    float* __restrict__ gout)
{
    __shared__ __align__(16) char smem[16384 + KSTR * 16 * 4];   // 25856 B
    const int tid = threadIdx.x;
    const int lane = tid & 63;

    // ================= kNN phase: 16 queries, 16 slices x 64 candidates =================
    {
        float4* s_cand = (float4*)smem;                 // 16384 B
        u32* lst_base  = (u32*)(smem + 16384);          // 16*KSTR*4 = 9472 B
        const int bk = blockIdx.x >> 6;                 // 64 blocks per batch
        const int i0 = (blockIdx.x & 63) << 4;          // 16 queries/block
        const int len = lengths[bk];
        const float* cb = coordsIn + (size_t)bk * SL * 3;
        for (int idx = tid; idx < SL; idx += 256) {
            const float* cp = cb + idx * 3;
            s_cand[idx] = make_float4(cp[0], cp[1], cp[2], 0.0f);
        }
        __syncthreads();

        const int q = tid & 15;
        const int s = tid >> 4;                          // slice 0..15
        const int i = i0 + q;
        const bool mi = i < len;
        const float4 qi = s_cand[i];
        const float xi = qi.x, yi = qi.y, zi = qi.z;

        u32 lst[8];
#pragma unroll
        for (int t = 0; t < 8; ++t) lst[t] = 0xFFFFFFFFu;

        const int jbase = s << 6;
#pragma unroll 4
        for (int jj = 0; jj < 64; ++jj) {
            const int j = jbase + ((jj + s) & 63);       // rotated visit: bank-disjoint
            const float4 cj = s_cand[j];
            const float dx = xi - cj.x, dy = yi - cj.y, dz = zi - cj.z;
            const float dist = dx * dx + dy * dy + dz * dz;
            const int dij = j - i;
            const bool pm = mi && (j < len);
            const bool adjx = (dij == 1) | (dij == -1);
            float v = pm ? (adjx ? 0.0f : dist) : 1e5f;
            v = (dij == 0) ? -1.0f : v;
            u32 bits = __float_as_uint(v);
            bits ^= (u32)((int)bits >> 31) | 0x80000000u;
            const u32 key = (bits & 0xFFFFFC00u) | (u32)j;
#pragma unroll
            for (int p = 7; p >= 1; --p)
                lst[p] = min(max(key, lst[p - 1]), lst[p]);
            lst[0] = min(key, lst[0]);
        }
#pragma unroll
        for (int t = 0; t < 8; ++t) lst_base[s * KSTR + q * 9 + t] = lst[t];
        __syncthreads();

        if (tid < 128) {
            const int p = tid >> 4, qq = tid & 15;
            u32 a[8], bb[8];
#pragma unroll
            for (int t = 0; t < 8; ++t) {
                a[t]  = lst_base[(2 * p) * KSTR + qq * 9 + t];
                bb[t] = lst_base[(2 * p + 1) * KSTR + qq * 9 + t];
            }
            merge8(a, bb);
#pragma unroll
            for (int t = 0; t < 8; ++t) lst_base[(2 * p) * KSTR + qq * 9 + t] = a[t];
        }
        __syncthreads();
        if (tid < 64) {
            const int p = tid >> 4, qq = tid & 15;
            u32 a[8], bb[8];
#pragma unroll
            for (int t = 0; t < 8; ++t) {
                a[t]  = lst_base[(4 * p) * KSTR + qq * 9 + t];
                bb[t] = lst_base[(4 * p + 2) * KSTR + qq * 9 + t];
            }
            merge8(a, bb);
#pragma unroll
            for (int t = 0; t < 8; ++t) lst_base[(4 * p) * KSTR + qq * 9 + t] = a[t];
        }
        __syncthreads();
        if (tid < 32) {
            const int p = tid >> 4, qq = tid & 15;
            u32 a[8], bb[8];
#pragma unroll
            for (int t = 0; t < 8; ++t) {
                a[t]  = lst_base[(8 * p) * KSTR + qq * 9 + t];
                bb[t] = lst_base[(8 * p + 4) * KSTR + qq * 9 + t];
            }
            merge8(a, bb);
#pragma unroll
            for (int t = 0; t < 8; ++t) lst_base[(8 * p) * KSTR + qq * 9 + t] = a[t];
        }
        __syncthreads();
        if (tid < 16) {
            const int qq = tid;
            u32 a[8], bb[8];
#pragma unroll
            for (int t = 0; t < 8; ++t) {
                a[t]  = lst_base[0 * KSTR + qq * 9 + t];
                bb[t] = lst_base[8 * KSTR + qq * 9 + t];
            }
            merge8(a, bb);
            const size_t node = (size_t)bk * SL + i0 + qq;
            int4 r0 = make_int4((int)(a[0] & 1023u), (int)(a[1] & 1023u), (int)(a[2] & 1023u), (int)(a[3] & 1023u));
            int4 r1 = make_int4((int)(a[4] & 1023u), (int)(a[5] & 1023u), (int)(a[6] & 1023u), (int)(a[7] & 1023u));
            ((int4*)idxbuf)[node * 2 + 0] = r0;
            ((int4*)idxbuf)[node * 2 + 1] = r1;
        }
    }
    __syncthreads();   // knn LDS readers done; this block's idxbuf rows visible (same L1)

    // ================= layer phase (r8 1-node lane-swap body) =================
    {
        float* s_w2e  = (float*)(smem);
        float* s_cw1  = (float*)(smem + 4608);
        float* s_nw1  = (float*)(smem + 8704);
        float* s_nw2  = (float*)(smem + 13312);
        float* s_w1r  = (float*)(smem + 15616);
        float* s_cw2v = (float*)(smem + 15904);
        float* s_cb1  = (float*)(smem + 16160);
        float* s_eb2  = (float*)(smem + 16416);
        float* s_lng  = (float*)(smem + 16480);
        float* s_lnb  = (float*)(smem + 16544);
        float* s_nb1  = (float*)(smem + 16608);
        float* s_nb2  = (float*)(smem + 16736);
        float* s_cb2  = (float*)(smem + 16800);

        for (int t = tid; t < 72 * 16; t += 256) s_w2e[t] = w2p[d * 72 * 16 + t];
        for (int t = tid; t < CH * 16; t += 256) s_cw1[t] = cw1t[d * CH * 16 + t];
        for (int t = tid; t < NHID * 32; t += 256) s_nw1[(t >> 5) * 36 + (t & 31)] = nw1t[d * NHID * 32 + t];
        for (int t = tid; t < 16 * 32; t += 256) s_nw2[(t >> 5) * 36 + (t & 31)] = nw2t[d * 16 * 32 + t];
        if (tid < 72) s_w1r[tid] = w1rp[d * 72 + tid];
        if (tid < CH) { s_cw2v[tid] = g_cw2[d * CH + tid]; s_cb1[tid] = g_cb1[d * CH + tid]; }
        if (tid < 16) {
            s_eb2[tid] = g_eb2[d * 16 + tid];
            s_lng[tid] = g_lng[d * 16 + tid];
            s_lnb[tid] = g_lnb[d * 16 + tid];
            s_nb2[tid] = g_nb2[d * 16 + tid];
        }
        if (tid < 32) s_nb1[tid] = g_nb1[d * 32 + tid];
        if (tid == 0) s_cb2[0] = g_cb2[d];

        const int h = (lane >> 3) & 1;
        const int k = lane & 7;
        const int sub = lane & 15;
        const int n = blockIdx.x * 16 + (tid >> 4);
        const int b = n >> 10;
        const int len = lengths[b];
        const int j = idxbuf[n * 8 + k];
        const bool em = ((n & 1023) < len) && (j < len);

        float ci[3], rel[3];
        {
            const float* cp = coordsIn + (size_t)n * 3;
            const float* cq = coordsIn + ((size_t)b * SL + j) * 3;
            ci[0] = cp[0]; ci[1] = cp[1]; ci[2] = cp[2];
            rel[0] = ci[0] - cq[0]; rel[1] = ci[1] - cq[1]; rel[2] = ci[2] - cq[2];
        }
        const float rd = fmaf(rel[0], rel[0], fmaf(rel[1], rel[1], rel[2] * rel[2]));

        const int ub = h * 36;
        const float* PiP = Pbuf + (size_t)n * PST + ub;
        const float* PjP = Pbuf + ((size_t)b * SL + j) * PST + 72 + ub;
        float4 pa = *(const float4*)PiP;
        float4 pb = *(const float4*)PjP;

        __syncthreads();   // weights staged

        float macc[16];
#pragma unroll
        for (int v = 0; v < 16; ++v) macc[v] = h ? 0.0f : s_eb2[v];
#pragma unroll
        for (int c4 = 0; c4 < 9; ++c4) {
            float4 na, nb;
            if (c4 < 8) {
                na = *(const float4*)(PiP + 4 * (c4 + 1));
                nb = *(const float4*)(PjP + 4 * (c4 + 1));
            }
            const int u0 = ub + c4 * 4;
            const float4 w1r4 = *(const float4*)&s_w1r[u0];
            const float hu0 = silu_f(fmaf(rd, w1r4.x, pa.x + pb.x));
            const float hu1 = silu_f(fmaf(rd, w1r4.y, pa.y + pb.y));
            const float hu2 = silu_f(fmaf(rd, w1r4.z, pa.z + pb.z));
            const float hu3 = silu_f(fmaf(rd, w1r4.w, pa.w + pb.w));
            const float* w2r = &s_w2e[u0 * 16];
#pragma unroll
            for (int v = 0; v < 16; ++v) {
                float m0 = fmaf(hu0, w2r[v], macc[v]);
                float m1 = fmaf(hu1, w2r[16 + v], m0);
                float m2 = fmaf(hu2, w2r[32 + v], m1);
                macc[v] = fmaf(hu3, w2r[48 + v], m2);
            }
            if (c4 < 8) { pa = na; pb = nb; }
        }

        // combine halves in-wave (partner = lane^8): macc becomes mm in place
#pragma unroll
        for (int v = 0; v < 16; ++v)
            macc[v] = silu_f(macc[v] + __shfl_xor(macc[v], 8, 64));

        const int tb = h * 32;
        float wa = 0.f;
#pragma unroll 4
        for (int tt = 0; tt < 32; ++tt) {
            const float* cr = &s_cw1[(tb + tt) * 16];
            float a0 = s_cb1[tb + tt], a1 = 0.f;
#pragma unroll
            for (int v = 0; v < 16; v += 2) {
                a0 = fmaf(macc[v], cr[v], a0);
                a1 = fmaf(macc[v + 1], cr[v + 1], a1);
            }
            wa = fmaf(silu_f(a0 + a1), s_cw2v[tb + tt], wa);
        }
        const float wao = __shfl_xor(wa, 8, 64);
        const float we = em ? (wa + wao + s_cb2[0]) : 0.f;

        float wr0 = we * rel[0], wr1 = we * rel[1], wr2 = we * rel[2];
#pragma unroll
        for (int s = 1; s < 8; s <<= 1) {
            wr0 += __shfl_xor(wr0, s, 64);
            wr1 += __shfl_xor(wr1, s, 64);
            wr2 += __shfl_xor(wr2, s, 64);
        }
        if ((lane & 15) == 0) {
            coordsOut[(size_t)n * 3 + 0] = ci[0] + wr0;
            coordsOut[(size_t)n * 3 + 1] = ci[1] + wr1;
            coordsOut[(size_t)n * 3 + 2] = ci[2] + wr2;
        }

        // m_i in place
#pragma unroll
        for (int v = 0; v < 16; ++v) {
            macc[v] = em ? macc[v] : 0.f;
#pragma unroll
            for (int s = 1; s < 8; s <<= 1)
                macc[v] += __shfl_xor(macc[v], s, 64);
        }
        // macc now holds m_i.

        float fi[16];
        {
            const float4* pp = (const float4*)(featsIn + (size_t)n * DIM);
            float4 a0 = pp[0], a1 = pp[1], a2 = pp[2], a3 = pp[3];
            fi[0]=a0.x; fi[1]=a0.y; fi[2]=a0.z; fi[3]=a0.w;
            fi[4]=a1.x; fi[5]=a1.y; fi[6]=a1.z; fi[7]=a1.w;
            fi[8]=a2.x; fi[9]=a2.y; fi[10]=a2.z; fi[11]=a2.w;
            fi[12]=a3.x; fi[13]=a3.y; fi[14]=a3.z; fi[15]=a3.w;
        }
        const float fiSub = featsIn[(size_t)n * DIM + sub];   // residual channel

        // LayerNorm: fi becomes nn in place
        {
            float mu = 0.f;
#pragma unroll
            for (int c = 0; c < 16; ++c) mu += fi[c];
            mu *= 0.0625f;
            float var = 0.f;
#pragma unroll
            for (int c = 0; c < 16; ++c) { const float dd = fi[c] - mu; var = fmaf(dd, dd, var); }
            var *= 0.0625f;
            const float rs = rsqrtf(var + LN_EPS);
#pragma unroll
            for (int c = 0; c < 16; ++c) fi[c] = fmaf((fi[c] - mu) * rs, s_lng[c], s_lnb[c]);
        }

        float nh[2];
#pragma unroll
        for (int q2 = 0; q2 < 2; ++q2) {
            const int u = sub * 2 + q2;
            const float* nr = &s_nw1[u * 36];
            float a0 = s_nb1[u], a1 = 0.f;
#pragma unroll
            for (int c = 0; c < 16; c += 2) {
                a0 = fmaf(fi[c], nr[c], a0);
                a1 = fmaf(fi[c + 1], nr[c + 1], a1);
            }
#pragma unroll
            for (int v = 0; v < 16; v += 2) {
                a0 = fmaf(macc[v], nr[16 + v], a0);
                a1 = fmaf(macc[v + 1], nr[16 + v + 1], a1);
            }
            nh[q2] = silu_f(a0 + a1);
        }

        const int nbase = lane & ~15;
        const float* w2c = &s_nw2[sub * 36];
        float o0 = s_nb2[sub];
#pragma unroll
        for (int u = 0; u < 32; ++u) {
            const float v = __shfl(nh[u & 1], nbase + (u >> 1), 64);
            o0 = fmaf(v, w2c[u], o0);
        }
        const float fo = fiSub + o0;
        featsOut[(size_t)n * DIM + sub] = fo;

        // gather new feats row (phi for d<2; final for d==2)
        float fr[16];
#pragma unroll
        for (int c = 0; c < 16; ++c) fr[c] = __shfl(fo, nbase + c, 64);

        if (d < 2) {
            const float* wbase = w1tp_all + (d + 1) * 132 * 16;
            const float* bbase = g_eb1 + (d + 1) * 66;
            float* Pout = PbufOut + (size_t)n * PST;
#pragma unroll
            for (int q2 = 0; q2 < 9; ++q2) {
                const int col = sub + (q2 << 4);
                const int ch = (col >= 108) ? 3 : (col >= 72) ? 2 : (col >= 36) ? 1 : 0;
                const int uu = col - ch * 36;
                const bool valid = uu < 33;
                const int u = ((ch & 1) ? 33 : 0) + uu;
                const int uc = valid ? u : 0;
                const int widx = valid ? ((ch < 2) ? u : 66 + u) : 0;
                float a0 = (valid && ch < 2) ? bbase[uc] : 0.0f;
                float a1 = 0.f, a2 = 0.f, a3 = 0.f;
                const float* wr = wbase + widx * 16;
#pragma unroll
                for (int cc = 0; cc < 16; cc += 4) {
                    a0 = fmaf(fr[cc + 0], wr[cc + 0], a0);
                    a1 = fmaf(fr[cc + 1], wr[cc + 1], a1);
                    a2 = fmaf(fr[cc + 2], wr[cc + 2], a2);
                    a3 = fmaf(fr[cc + 3], wr[cc + 3], a3);
                }
                Pout[col] = valid ? ((a0 + a1) + (a2 + a3)) : 0.0f;
            }
        } else {
            // fused final projection: lanes sub<3 compute output channel sub
            if (sub < 3) {
                float acc = fb[sub];
#pragma unroll
                for (int c = 0; c < 16; ++c)
                    acc = fmaf(fr[c], fw[c * 3 + sub], acc);
                gout[(size_t)n * 3 + sub] = acc;
            }
        }
    }
}

extern "C" void kernel_launch(void* const* d_in, const int* in_sizes, int n_in,
                              void* d_out, int out_size, void* d_ws, size_t ws_size,
                              hipStream_t stream) {
    const float* coords    = (const float*)d_in[0];
    const int*   residues  = (const int*)d_in[1];
    const int*   lengths   = (const int*)d_in[2];
    const float* token_emb = (const float*)d_in[3];
    const float* pos_emb   = (const float*)d_in[4];
    const float* ew1 = (const float*)d_in[5];
    const float* eb1 = (const float*)d_in[6];
    const float* ew2 = (const float*)d_in[7];
    const float* eb2 = (const float*)d_in[8];
    const float* cw1 = (const float*)d_in[9];
    const float* cb1 = (const float*)d_in[10];
    const float* cw2 = (const float*)d_in[11];
    const float* cb2 = (const float*)d_in[12];
    const float* lng = (const float*)d_in[13];
    const float* lnb = (const float*)d_in[14];
    const float* nw1 = (const float*)d_in[15];
    const float* nb1 = (const float*)d_in[16];
    const float* nw2 = (const float*)d_in[17];
    const float* nb2 = (const float*)d_in[18];
    const float* fw  = (const float*)d_in[19];
    const float* fb  = (const float*)d_in[20];

    float* ws = (float*)d_ws;
    float* coordsA = ws;
    float* coordsB = coordsA + NB * SL * 3;
    float* featsA  = coordsB + NB * SL * 3;
    float* featsB  = featsA + NB * SL * DIM;
    int*   idxbuf  = (int*)(featsB + NB * SL * DIM);
    float* w1tp = (float*)(idxbuf + NB * SL * KNN);     // 3*132*16
    float* w1rp = w1tp + 3 * 132 * 16;                  // 3*72
    float* w2p  = w1rp + 3 * 72;                        // 3*72*16
    float* cw1t = w2p + 3 * 72 * 16;                    // 3*64*16
    float* nw1t = cw1t + 3 * CH * 16;                   // 3*32*32
    float* nw2t = nw1t + 3 * NHID * 32;                 // 3*16*32
    float* PbufA = nw2t + 3 * 16 * 32;                  // 16384*144
    float* PbufB = PbufA + (size_t)NB * SL * PST;       // 16384*144
    float* gout  = (float*)d_out;

    pack_kernel<<<32, 256, 0, stream>>>(ew1, ew2, cw1, nw1, nw2, w1tp, w1rp, w2p, cw1t, nw1t, nw2t);
    init_kernel<<<NB * SL * 4 / 256, 256, 0, stream>>>(coords, residues, token_emb, pos_emb,
                                                        w1tp, eb1, coordsA, featsA, PbufA);

    float* cIn = coordsA; float* cOut = coordsB;
    float* fIn = featsA;  float* fOut = featsB;
    float* pIn = PbufA;   float* pOut = PbufB;
    for (int d = 0; d < 3; ++d) {
        fused_kernel<<<NB * SL / 16, 256, 0, stream>>>(d, cIn, cOut, fIn, fOut, pIn, pOut,
            idxbuf, lengths,
            w1rp, w2p, eb2, cw1t, cb1, cw2, cb2, lng, lnb, nw1t, nb1, nw2t, nb2,
            w1tp, eb1, fw, fb, gout);
        float* t;
        t = cIn; cIn = cOut; cOut = t;
        t = fIn; fIn = fOut; fOut = t;
        t = pIn; pIn = pOut; pOut = t;
    }
}

// Round 17
// 250.843 us; speedup vs baseline: 1.0559x; 1.0514x over previous
//
#include <hip/hip_runtime.h>
#include <math.h>

typedef unsigned long long u64;
typedef unsigned int u32;

#define NB 16
#define SL 1024
#define DIM 16
#define KNN 8
#define CH 64    /* coors hidden */
#define NHID 32  /* node hidden */
#define LN_EPS 1e-5f
#define PST 144  /* P row stride: 4 chunks of 36 (33 units + 3 zero pad) */
#define KSTR 148 /* knn lst scratch: words per slice (16 q * 9 + 4 pad) */

// silu via hw exp + hw rcp: 5 VALU vs ~12 for div-based (no -ffast-math here)
__device__ __forceinline__ float silu_f(float x) {
    const float e = __expf(-x);
    return x * __builtin_amdgcn_rcpf(1.0f + e);
}

// ---------------- init: feats/coords copy + fused phi for layer 0 ----------------
__global__ __launch_bounds__(256) void init_kernel(
    const float* __restrict__ coords, const int* __restrict__ residues,
    const float* __restrict__ token_emb, const float* __restrict__ pos_emb,
    const float* __restrict__ w1tp, const float* __restrict__ g_eb1,
    float* __restrict__ coordsA, float* __restrict__ featsA,
    float* __restrict__ Pout)
{
    const int t = blockIdx.x * 256 + threadIdx.x;
    const int node = t >> 2;
    const int part = t & 3;
    const int l = node & (SL - 1);
    const int r = residues[node];
    float f[16];
    {
        const float4* te = (const float4*)(token_emb + (size_t)r * DIM);
        const float4* pe = (const float4*)(pos_emb + (size_t)l * DIM);
#pragma unroll
        for (int q = 0; q < 4; ++q) {
            float4 a = te[q], b4 = pe[q];
            f[4*q+0] = a.x + b4.x; f[4*q+1] = a.y + b4.y;
            f[4*q+2] = a.z + b4.z; f[4*q+3] = a.w + b4.w;
        }
    }
    if (part == 0) {
        float4* fo = (float4*)(featsA + (size_t)node * DIM);
#pragma unroll
        for (int q = 0; q < 4; ++q)
            fo[q] = make_float4(f[4*q], f[4*q+1], f[4*q+2], f[4*q+3]);
        coordsA[node * 3 + 0] = coords[node * 3 + 0];
        coordsA[node * 3 + 1] = coords[node * 3 + 1];
        coordsA[node * 3 + 2] = coords[node * 3 + 2];
    }
    const int ubase = (part & 1) * 33;
    const int wbase = (part < 2) ? 0 : 66;
    float res[36];
    res[33] = 0.f; res[34] = 0.f; res[35] = 0.f;
#pragma unroll
    for (int oo = 0; oo < 33; ++oo) {     // FULL unroll: res[] stays in registers
        const int u = ubase + oo;
        const float* wr = w1tp + (wbase + u) * 16;
        float a0 = (part < 2) ? g_eb1[u] : 0.0f;
        float a1 = 0.f, a2 = 0.f, a3 = 0.f;
#pragma unroll
        for (int c = 0; c < 16; c += 4) {
            a0 = fmaf(f[c + 0], wr[c + 0], a0);
            a1 = fmaf(f[c + 1], wr[c + 1], a1);
            a2 = fmaf(f[c + 2], wr[c + 2], a2);
            a3 = fmaf(f[c + 3], wr[c + 3], a3);
        }
        res[oo] = (a0 + a1) + (a2 + a3);
    }
    float4* op = (float4*)(Pout + (size_t)node * PST + part * 36);
#pragma unroll
    for (int q = 0; q < 9; ++q)
        op[q] = make_float4(res[4*q], res[4*q+1], res[4*q+2], res[4*q+3]);
}

// ---------------- weight transpose/pack ----------------
__global__ __launch_bounds__(256) void pack_kernel(
    const float* __restrict__ ew1, const float* __restrict__ ew2,
    const float* __restrict__ cw1,
    const float* __restrict__ nw1, const float* __restrict__ nw2,
    float* __restrict__ w1tp, float* __restrict__ w1rp, float* __restrict__ w2p,
    float* __restrict__ cw1t, float* __restrict__ nw1t, float* __restrict__ nw2t)
{
    const int stride = gridDim.x * 256;
    const int t0 = blockIdx.x * 256 + threadIdx.x;
    for (int idx = t0; idx < 3 * 132 * 16; idx += stride) {
        int d = idx / (132 * 16); int r = idx - d * 132 * 16; int o = r >> 4; int c = r & 15;
        int u = (o < 66) ? o : (o - 66);
        int cc = (o < 66) ? c : (16 + c);
        w1tp[idx] = ew1[(d * 33 + cc) * 66 + u];
    }
    for (int idx = t0; idx < 3 * 72; idx += stride) {
        int d = idx / 72; int o = idx - d * 72; int hh = o / 36; int uu = o - hh * 36;
        w1rp[idx] = (uu < 33) ? ew1[(d * 33 + 32) * 66 + hh * 33 + uu] : 0.0f;
    }
    for (int idx = t0; idx < 3 * 72 * 16; idx += stride) {
        int d = idx / (72 * 16); int r = idx - d * 72 * 16; int u = r >> 4; int v = r & 15;
        int hh = u / 36; int uu = u - hh * 36;
        w2p[idx] = (uu < 33) ? ew2[(d * 66 + hh * 33 + uu) * 16 + v] : 0.0f;
    }
    for (int idx = t0; idx < 3 * CH * 16; idx += stride) {
        int d = idx / (CH * 16); int r = idx - d * CH * 16; int t = r >> 4; int v = r & 15;
        cw1t[(d * CH + t) * 16 + v] = cw1[(d * 16 + v) * CH + t];
    }
    for (int idx = t0; idx < 3 * NHID * 32; idx += stride) {
        int d = idx / (NHID * 32); int r = idx - d * NHID * 32; int u = r >> 5; int c = r & 31;
        nw1t[(d * NHID + u) * 32 + c] = nw1[(d * 32 + c) * NHID + u];
    }
    for (int idx = t0; idx < 3 * 16 * 32; idx += stride) {
        int d = idx / (16 * 32); int r = idx - d * 16 * 32; int c = r >> 5; int u = r & 31;
        nw2t[(d * 16 + c) * 32 + u] = nw2[(d * 32 + u) * 16 + c];
    }
}

__device__ __forceinline__ void merge8(u32* a, const u32* bb) {
    u32 c[8];
#pragma unroll
    for (int t = 0; t < 8; ++t) c[t] = min(a[t], bb[7 - t]);
#define MCAS(x, y) { u32 mn = min(c[x], c[y]); u32 mx = max(c[x], c[y]); c[x] = mn; c[y] = mx; }
    MCAS(0, 4) MCAS(1, 5) MCAS(2, 6) MCAS(3, 7)
    MCAS(0, 2) MCAS(1, 3) MCAS(4, 6) MCAS(5, 7)
    MCAS(0, 1) MCAS(2, 3) MCAS(4, 5) MCAS(6, 7)
#undef MCAS
#pragma unroll
    for (int t = 0; t < 8; ++t) a[t] = c[t];
}

// ---------------- FUSED knn+layer for one d, 16 nodes/block ----------------
// Occupancy table (measured): hint=4 -> 30% occ / 51.2us (best, r14); hint=3/none ->
// 23% / 54.8; hint=2 -> 20% / 67. The hint RAISES residency on this toolchain, so we
// keep (256,4) and instead diet the registers to fit the 64-VGPR squeeze without the
// r14 spills: P chunks are read directly in-loop (no prefetch pair, -8..12 live regs;
// L2 latency covered by 4-block TLP). Keep rotation + KSTR=148 (conflict fixes, r15).
// Cooperative launch NOT capture-safe (r12). 1e5 sentinel load-bearing (r4/r5).
__global__ __launch_bounds__(256, 4) void fused_kernel(
    const int d,
    const float* __restrict__ coordsIn, float* __restrict__ coordsOut,
    const float* __restrict__ featsIn, float* __restrict__ featsOut,
    const float* __restrict__ Pbuf, float* __restrict__ PbufOut,
    int* __restrict__ idxbuf, const int* __restrict__ lengths,
    const float* __restrict__ w1rp, const float* __restrict__ w2p,
    const float* __restrict__ g_eb2,
    const float* __restrict__ cw1t, const float* __restrict__ g_cb1,
    const float* __restrict__ g_cw2, const float* __restrict__ g_cb2,
    const float* __restrict__ g_lng, const float* __restrict__ g_lnb,
    const float* __restrict__ nw1t, const float* __restrict__ g_nb1,
    const float* __restrict__ nw2t, const float* __restrict__ g_nb2,
    const float* __restrict__ w1tp_all, const float* __restrict__ g_eb1,
    const float* __restrict__ fw, const float* __restrict__ fb,
    float* __restrict__ gout)
{
    __shared__ __align__(16) char smem[16384 + KSTR * 16 * 4];   // 25856 B
    const int tid = threadIdx.x;
    const int lane = tid & 63;

    // ================= kNN phase: 16 queries, 16 slices x 64 candidates =================
    {
        float4* s_cand = (float4*)smem;                 // 16384 B
        u32* lst_base  = (u32*)(smem + 16384);          // 16*KSTR*4 = 9472 B
        const int bk = blockIdx.x >> 6;                 // 64 blocks per batch
        const int i0 = (blockIdx.x & 63) << 4;          // 16 queries/block
        const int len = lengths[bk];
        const float* cb = coordsIn + (size_t)bk * SL * 3;
        for (int idx = tid; idx < SL; idx += 256) {
            const float* cp = cb + idx * 3;
            s_cand[idx] = make_float4(cp[0], cp[1], cp[2], 0.0f);
        }
        __syncthreads();

        const int q = tid & 15;
        const int s = tid >> 4;                          // slice 0..15
        const int i = i0 + q;
        const bool mi = i < len;
        const float4 qi = s_cand[i];
        const float xi = qi.x, yi = qi.y, zi = qi.z;

        u32 lst[8];
#pragma unroll
        for (int t = 0; t < 8; ++t) lst[t] = 0xFFFFFFFFu;

        const int jbase = s << 6;
#pragma unroll 4
        for (int jj = 0; jj < 64; ++jj) {
            const int j = jbase + ((jj + s) & 63);       // rotated visit: bank-disjoint
            const float4 cj = s_cand[j];
            const float dx = xi - cj.x, dy = yi - cj.y, dz = zi - cj.z;
            const float dist = dx * dx + dy * dy + dz * dz;
            const int dij = j - i;
            const bool pm = mi && (j < len);
            const bool adjx = (dij == 1) | (dij == -1);
            float v = pm ? (adjx ? 0.0f : dist) : 1e5f;
            v = (dij == 0) ? -1.0f : v;
            u32 bits = __float_as_uint(v);
            bits ^= (u32)((int)bits >> 31) | 0x80000000u;
            const u32 key = (bits & 0xFFFFFC00u) | (u32)j;
#pragma unroll
            for (int p = 7; p >= 1; --p)
                lst[p] = min(max(key, lst[p - 1]), lst[p]);
            lst[0] = min(key, lst[0]);
        }
#pragma unroll
        for (int t = 0; t < 8; ++t) lst_base[s * KSTR + q * 9 + t] = lst[t];
        __syncthreads();

        if (tid < 128) {
            const int p = tid >> 4, qq = tid & 15;
            u32 a[8], bb[8];
#pragma unroll
            for (int t = 0; t < 8; ++t) {
                a[t]  = lst_base[(2 * p) * KSTR + qq * 9 + t];
                bb[t] = lst_base[(2 * p + 1) * KSTR + qq * 9 + t];
            }
            merge8(a, bb);
#pragma unroll
            for (int t = 0; t < 8; ++t) lst_base[(2 * p) * KSTR + qq * 9 + t] = a[t];
        }
        __syncthreads();
        if (tid < 64) {
            const int p = tid >> 4, qq = tid & 15;
            u32 a[8], bb[8];
#pragma unroll
            for (int t = 0; t < 8; ++t) {
                a[t]  = lst_base[(4 * p) * KSTR + qq * 9 + t];
                bb[t] = lst_base[(4 * p + 2) * KSTR + qq * 9 + t];
            }
            merge8(a, bb);
#pragma unroll
            for (int t = 0; t < 8; ++t) lst_base[(4 * p) * KSTR + qq * 9 + t] = a[t];
        }
        __syncthreads();
        if (tid < 32) {
            const int p = tid >> 4, qq = tid & 15;
            u32 a[8], bb[8];
#pragma unroll
            for (int t = 0; t < 8; ++t) {
                a[t]  = lst_base[(8 * p) * KSTR + qq * 9 + t];
                bb[t] = lst_base[(8 * p + 4) * KSTR + qq * 9 + t];
            }
            merge8(a, bb);
#pragma unroll
            for (int t = 0; t < 8; ++t) lst_base[(8 * p) * KSTR + qq * 9 + t] = a[t];
        }
        __syncthreads();
        if (tid < 16) {
            const int qq = tid;
            u32 a[8], bb[8];
#pragma unroll
            for (int t = 0; t < 8; ++t) {
                a[t]  = lst_base[0 * KSTR + qq * 9 + t];
                bb[t] = lst_base[8 * KSTR + qq * 9 + t];
            }
            merge8(a, bb);
            const size_t node = (size_t)bk * SL + i0 + qq;
            int4 r0 = make_int4((int)(a[0] & 1023u), (int)(a[1] & 1023u), (int)(a[2] & 1023u), (int)(a[3] & 1023u));
            int4 r1 = make_int4((int)(a[4] & 1023u), (int)(a[5] & 1023u), (int)(a[6] & 1023u), (int)(a[7] & 1023u));
            ((int4*)idxbuf)[node * 2 + 0] = r0;
            ((int4*)idxbuf)[node * 2 + 1] = r1;
        }
    }
    __syncthreads();   // knn LDS readers done; this block's idxbuf rows visible (same L1)

    // ================= layer phase (r8 1-node lane-swap body, streamed P) =================
    {
        float* s_w2e  = (float*)(smem);
        float* s_cw1  = (float*)(smem + 4608);
        float* s_nw1  = (float*)(smem + 8704);
        float* s_nw2  = (float*)(smem + 13312);
        float* s_w1r  = (float*)(smem + 15616);
        float* s_cw2v = (float*)(smem + 15904);
        float* s_cb1  = (float*)(smem + 16160);
        float* s_eb2  = (float*)(smem + 16416);
        float* s_lng  = (float*)(smem + 16480);
        float* s_lnb  = (float*)(smem + 16544);
        float* s_nb1  = (float*)(smem + 16608);
        float* s_nb2  = (float*)(smem + 16736);
        float* s_cb2  = (float*)(smem + 16800);

        for (int t = tid; t < 72 * 16; t += 256) s_w2e[t] = w2p[d * 72 * 16 + t];
        for (int t = tid; t < CH * 16; t += 256) s_cw1[t] = cw1t[d * CH * 16 + t];
        for (int t = tid; t < NHID * 32; t += 256) s_nw1[(t >> 5) * 36 + (t & 31)] = nw1t[d * NHID * 32 + t];
        for (int t = tid; t < 16 * 32; t += 256) s_nw2[(t >> 5) * 36 + (t & 31)] = nw2t[d * 16 * 32 + t];
        if (tid < 72) s_w1r[tid] = w1rp[d * 72 + tid];
        if (tid < CH) { s_cw2v[tid] = g_cw2[d * CH + tid]; s_cb1[tid] = g_cb1[d * CH + tid]; }
        if (tid < 16) {
            s_eb2[tid] = g_eb2[d * 16 + tid];
            s_lng[tid] = g_lng[d * 16 + tid];
            s_lnb[tid] = g_lnb[d * 16 + tid];
            s_nb2[tid] = g_nb2[d * 16 + tid];
        }
        if (tid < 32) s_nb1[tid] = g_nb1[d * 32 + tid];
        if (tid == 0) s_cb2[0] = g_cb2[d];

        const int h = (lane >> 3) & 1;
        const int k = lane & 7;
        const int sub = lane & 15;
        const int n = blockIdx.x * 16 + (tid >> 4);
        const int b = n >> 10;
        const int len = lengths[b];
        const int j = idxbuf[n * 8 + k];
        const bool em = ((n & 1023) < len) && (j < len);

        float ci[3], rel[3];
        {
            const float* cp = coordsIn + (size_t)n * 3;
            const float* cq = coordsIn + ((size_t)b * SL + j) * 3;
            ci[0] = cp[0]; ci[1] = cp[1]; ci[2] = cp[2];
            rel[0] = ci[0] - cq[0]; rel[1] = ci[1] - cq[1]; rel[2] = ci[2] - cq[2];
        }
        const float rd = fmaf(rel[0], rel[0], fmaf(rel[1], rel[1], rel[2] * rel[2]));

        const int ub = h * 36;
        const float* PiP = Pbuf + (size_t)n * PST + ub;
        const float* PjP = Pbuf + ((size_t)b * SL + j) * PST + 72 + ub;

        __syncthreads();   // weights staged

        float macc[16];
#pragma unroll
        for (int v = 0; v < 16; ++v) macc[v] = h ? 0.0f : s_eb2[v];
#pragma unroll
        for (int c4 = 0; c4 < 9; ++c4) {
            const float4 pa = *(const float4*)(PiP + 4 * c4);   // streamed: no prefetch regs
            const float4 pb = *(const float4*)(PjP + 4 * c4);
            const int u0 = ub + c4 * 4;
            const float4 w1r4 = *(const float4*)&s_w1r[u0];
            const float hu0 = silu_f(fmaf(rd, w1r4.x, pa.x + pb.x));
            const float hu1 = silu_f(fmaf(rd, w1r4.y, pa.y + pb.y));
            const float hu2 = silu_f(fmaf(rd, w1r4.z, pa.z + pb.z));
            const float hu3 = silu_f(fmaf(rd, w1r4.w, pa.w + pb.w));
            const float* w2r = &s_w2e[u0 * 16];
#pragma unroll
            for (int v = 0; v < 16; ++v) {
                float m0 = fmaf(hu0, w2r[v], macc[v]);
                float m1 = fmaf(hu1, w2r[16 + v], m0);
                float m2 = fmaf(hu2, w2r[32 + v], m1);
                macc[v] = fmaf(hu3, w2r[48 + v], m2);
            }
        }

        // combine halves in-wave (partner = lane^8): macc becomes mm in place
#pragma unroll
        for (int v = 0; v < 16; ++v)
            macc[v] = silu_f(macc[v] + __shfl_xor(macc[v], 8, 64));

        const int tb = h * 32;
        float wa = 0.f;
#pragma unroll 4
        for (int tt = 0; tt < 32; ++tt) {
            const float* cr = &s_cw1[(tb + tt) * 16];
            float a0 = s_cb1[tb + tt], a1 = 0.f;
#pragma unroll
            for (int v = 0; v < 16; v += 2) {
                a0 = fmaf(macc[v], cr[v], a0);
                a1 = fmaf(macc[v + 1], cr[v + 1], a1);
            }
            wa = fmaf(silu_f(a0 + a1), s_cw2v[tb + tt], wa);
        }
        const float wao = __shfl_xor(wa, 8, 64);
        const float we = em ? (wa + wao + s_cb2[0]) : 0.f;

        float wr0 = we * rel[0], wr1 = we * rel[1], wr2 = we * rel[2];
#pragma unroll
        for (int s = 1; s < 8; s <<= 1) {
            wr0 += __shfl_xor(wr0, s, 64);
            wr1 += __shfl_xor(wr1, s, 64);
            wr2 += __shfl_xor(wr2, s, 64);
        }
        if ((lane & 15) == 0) {
            coordsOut[(size_t)n * 3 + 0] = ci[0] + wr0;
            coordsOut[(size_t)n * 3 + 1] = ci[1] + wr1;
            coordsOut[(size_t)n * 3 + 2] = ci[2] + wr2;
        }

        // m_i in place
#pragma unroll
        for (int v = 0; v < 16; ++v) {
            macc[v] = em ? macc[v] : 0.f;
#pragma unroll
            for (int s = 1; s < 8; s <<= 1)
                macc[v] += __shfl_xor(macc[v], s, 64);
        }
        // macc now holds m_i.

        float fi[16];
        {
            const float4* pp = (const float4*)(featsIn + (size_t)n * DIM);
            float4 a0 = pp[0], a1 = pp[1], a2 = pp[2], a3 = pp[3];
            fi[0]=a0.x; fi[1]=a0.y; fi[2]=a0.z; fi[3]=a0.w;
            fi[4]=a1.x; fi[5]=a1.y; fi[6]=a1.z; fi[7]=a1.w;
            fi[8]=a2.x; fi[9]=a2.y; fi[10]=a2.z; fi[11]=a2.w;
            fi[12]=a3.x; fi[13]=a3.y; fi[14]=a3.z; fi[15]=a3.w;
        }
        const float fiSub = featsIn[(size_t)n * DIM + sub];   // residual channel

        // LayerNorm: fi becomes nn in place
        {
            float mu = 0.f;
#pragma unroll
            for (int c = 0; c < 16; ++c) mu += fi[c];
            mu *= 0.0625f;
            float var = 0.f;
#pragma unroll
            for (int c = 0; c < 16; ++c) { const float dd = fi[c] - mu; var = fmaf(dd, dd, var); }
            var *= 0.0625f;
            const float rs = rsqrtf(var + LN_EPS);
#pragma unroll
            for (int c = 0; c < 16; ++c) fi[c] = fmaf((fi[c] - mu) * rs, s_lng[c], s_lnb[c]);
        }

        float nh[2];
#pragma unroll
        for (int q2 = 0; q2 < 2; ++q2) {
            const int u = sub * 2 + q2;
            const float* nr = &s_nw1[u * 36];
            float a0 = s_nb1[u], a1 = 0.f;
#pragma unroll
            for (int c = 0; c < 16; c += 2) {
                a0 = fmaf(fi[c], nr[c], a0);
                a1 = fmaf(fi[c + 1], nr[c + 1], a1);
            }
#pragma unroll
            for (int v = 0; v < 16; v += 2) {
                a0 = fmaf(macc[v], nr[16 + v], a0);
                a1 = fmaf(macc[v + 1], nr[16 + v + 1], a1);
            }
            nh[q2] = silu_f(a0 + a1);
        }

        const int nbase = lane & ~15;
        const float* w2c = &s_nw2[sub * 36];
        float o0 = s_nb2[sub];
#pragma unroll
        for (int u = 0; u < 32; ++u) {
            const float v = __shfl(nh[u & 1], nbase + (u >> 1), 64);
            o0 = fmaf(v, w2c[u], o0);
        }
        const float fo = fiSub + o0;
        featsOut[(size_t)n * DIM + sub] = fo;

        // gather new feats row (phi for d<2; final for d==2)
        float fr[16];
#pragma unroll
        for (int c = 0; c < 16; ++c) fr[c] = __shfl(fo, nbase + c, 64);

        if (d < 2) {
            const float* wbase = w1tp_all + (d + 1) * 132 * 16;
            const float* bbase = g_eb1 + (d + 1) * 66;
            float* Pout = PbufOut + (size_t)n * PST;
#pragma unroll
            for (int q2 = 0; q2 < 9; ++q2) {
                const int col = sub + (q2 << 4);
                const int ch = (col >= 108) ? 3 : (col >= 72) ? 2 : (col >= 36) ? 1 : 0;
                const int uu = col - ch * 36;
                const bool valid = uu < 33;
                const int u = ((ch & 1) ? 33 : 0) + uu;
                const int uc = valid ? u : 0;
                const int widx = valid ? ((ch < 2) ? u : 66 + u) : 0;
                float a0 = (valid && ch < 2) ? bbase[uc] : 0.0f;
                float a1 = 0.f, a2 = 0.f, a3 = 0.f;
                const float* wr = wbase + widx * 16;
#pragma unroll
                for (int cc = 0; cc < 16; cc += 4) {
                    a0 = fmaf(fr[cc + 0], wr[cc + 0], a0);
                    a1 = fmaf(fr[cc + 1], wr[cc + 1], a1);
                    a2 = fmaf(fr[cc + 2], wr[cc + 2], a2);
                    a3 = fmaf(fr[cc + 3], wr[cc + 3], a3);
                }
                Pout[col] = valid ? ((a0 + a1) + (a2 + a3)) : 0.0f;
            }
        } else {
            // fused final projection: lanes sub<3 compute output channel sub
            if (sub < 3) {
                float acc = fb[sub];
#pragma unroll
                for (int c = 0; c < 16; ++c)
                    acc = fmaf(fr[c], fw[c * 3 + sub], acc);
                gout[(size_t)n * 3 + sub] = acc;
            }
        }
    }
}

extern "C" void kernel_launch(void* const* d_in, const int* in_sizes, int n_in,
                              void* d_out, int out_size, void* d_ws, size_t ws_size,
                              hipStream_t stream) {
    const float* coords    = (const float*)d_in[0];
    const int*   residues  = (const int*)d_in[1];
    const int*   lengths   = (const int*)d_in[2];
    const float* token_emb = (const float*)d_in[3];
    const float* pos_emb   = (const float*)d_in[4];
    const float* ew1 = (const float*)d_in[5];
    const float* eb1 = (const float*)d_in[6];
    const float* ew2 = (const float*)d_in[7];
    const float* eb2 = (const float*)d_in[8];
    const float* cw1 = (const float*)d_in[9];
    const float* cb1 = (const float*)d_in[10];
    const float* cw2 = (const float*)d_in[11];
    const float* cb2 = (const float*)d_in[12];
    const float* lng = (const float*)d_in[13];
    const float* lnb = (const float*)d_in[14];
    const float* nw1 = (const float*)d_in[15];
    const float* nb1 = (const float*)d_in[16];
    const float* nw2 = (const float*)d_in[17];
    const float* nb2 = (const float*)d_in[18];
    const float* fw  = (const float*)d_in[19];
    const float* fb  = (const float*)d_in[20];

    float* ws = (float*)d_ws;
    float* coordsA = ws;
    float* coordsB = coordsA + NB * SL * 3;
    float* featsA  = coordsB + NB * SL * 3;
    float* featsB  = featsA + NB * SL * DIM;
    int*   idxbuf  = (int*)(featsB + NB * SL * DIM);
    float* w1tp = (float*)(idxbuf + NB * SL * KNN);     // 3*132*16
    float* w1rp = w1tp + 3 * 132 * 16;                  // 3*72
    float* w2p  = w1rp + 3 * 72;                        // 3*72*16
    float* cw1t = w2p + 3 * 72 * 16;                    // 3*64*16
    float* nw1t = cw1t + 3 * CH * 16;                   // 3*32*32
    float* nw2t = nw1t + 3 * NHID * 32;                 // 3*16*32
    float* PbufA = nw2t + 3 * 16 * 32;                  // 16384*144
    float* PbufB = PbufA + (size_t)NB * SL * PST;       // 16384*144
    float* gout  = (float*)d_out;

    pack_kernel<<<32, 256, 0, stream>>>(ew1, ew2, cw1, nw1, nw2, w1tp, w1rp, w2p, cw1t, nw1t, nw2t);
    init_kernel<<<NB * SL * 4 / 256, 256, 0, stream>>>(coords, residues, token_emb, pos_emb,
                                                        w1tp, eb1, coordsA, featsA, PbufA);

    float* cIn = coordsA; float* cOut = coordsB;
    float* fIn = featsA;  float* fOut = featsB;
    float* pIn = PbufA;   float* pOut = PbufB;
    for (int d = 0; d < 3; ++d) {
        fused_kernel<<<NB * SL / 16, 256, 0, stream>>>(d, cIn, cOut, fIn, fOut, pIn, pOut,
            idxbuf, lengths,
            w1rp, w2p, eb2, cw1t, cb1, cw2, cb2, lng, lnb, nw1t, nb1, nw2t, nb2,
            w1tp, eb1, fw, fb, gout);
        float* t;
        t = cIn; cIn = cOut; cOut = t;
        t = fIn; fIn = fOut; fOut = t;
        t = pIn; pIn = pOut; pOut = t;
    }
}